// Round 1
// baseline (230.447 us; speedup 1.0000x reference)
//
#include <hip/hip_runtime.h>
#include <hip/hip_bf16.h>

// Problem: B=4, C=256, N=4096 (16^3).
// out[b,c,n] = sum_m relu(cos(x_n,x_m))^2 * (W x + b)[c,m]
// = sum_m relu(Sraw[n,m])^2 * nv2[n]*nv2[m] * T[c,m],  nv2 = 1/max(||x_n||,eps)^2

typedef unsigned short u16;
typedef __attribute__((ext_vector_type(8))) short short8;   // 8 bf16 = 4 VGPRs
typedef __attribute__((ext_vector_type(4))) float f32x4;

#define MFMA16(a, b, c) __builtin_amdgcn_mfma_f32_16x16x32_bf16((a), (b), (c), 0, 0, 0)

__device__ __forceinline__ u16 f2bf(float f) {
    union { float f; unsigned u; } v; v.f = f;
    unsigned u = v.u;
    u += 0x7fffu + ((u >> 16) & 1u);   // RNE
    return (u16)(u >> 16);
}

// ---------------- K0: W (fp32 256x256) -> bf16 ----------------
__global__ void k_wconv(const float* __restrict__ W, u16* __restrict__ Wbf) {
    int i = blockIdx.x * 256 + threadIdx.x;   // grid 256 -> 65536 threads
    Wbf[i] = f2bf(W[i]);
}

// ---------------- K1a: nv2[b,n] = 1/max(||x[:,n]||^2, eps^2) ----------------
__global__ void k_norm(const float* __restrict__ x, float* __restrict__ nv2) {
    int idx = blockIdx.x * 256 + threadIdx.x;   // 16384 = B*N
    int b = idx >> 12, n = idx & 4095;
    const float* p = x + ((size_t)b << 20) + n;
    float s = 0.f;
#pragma unroll 8
    for (int c = 0; c < 256; ++c) {
        float v = p[(size_t)c << 12];
        s += v * v;
    }
    nv2[idx] = 1.0f / fmaxf(s, 1e-16f);   // = 1/max(sqrt(s),1e-8)^2
}

// ---------------- K1b: xfT[b][n][c] = bf16(x[b][c][n]) (LDS transpose) ------
__global__ __launch_bounds__(256) void k_xpose(const float* __restrict__ x,
                                               u16* __restrict__ xfT) {
    __shared__ u16 tl[64][68];   // +4 pad: 2-way banks on column reads
    int bid = blockIdx.x;                    // 1024 = 4 * 4 * 64
    int b = bid >> 8, rem = bid & 255, ct = rem >> 6, nt = rem & 63;
    int c0 = ct << 6, n0 = nt << 6;
    int tid = threadIdx.x;
    int rr = tid >> 6, cc = tid & 63;
    const float* xp = x + ((size_t)b << 20) + (size_t)c0 * 4096 + n0;
#pragma unroll
    for (int s = 0; s < 16; ++s) {
        int row = (s << 2) + rr;                       // c_loc
        tl[row][cc] = f2bf(xp[(size_t)row * 4096 + cc]);
    }
    __syncthreads();
    u16* op = xfT + ((size_t)b << 20) + (size_t)n0 * 256 + c0;
#pragma unroll
    for (int s = 0; s < 16; ++s) {
        int row = (s << 2) + rr;                       // n_loc
        op[(size_t)row * 256 + cc] = tl[cc][row];
    }
}

// ---------------- K2: T = W x + bias -> tb bf16 [b][c][n] -------------------
// grid 512: batch = bid>>7, 32-wide n-tile. 4 waves; wave w: c in [64w,64w+64).
__global__ __launch_bounds__(256) void k_tgemm(const u16* __restrict__ Wbf,
                                               const u16* __restrict__ xfT,
                                               const float* __restrict__ bias,
                                               u16* __restrict__ tb) {
    int bid = blockIdx.x;
    int batch = bid >> 7, nt = bid & 127;
    int n0 = nt << 5;
    const u16* xf_b = xfT + ((size_t)batch << 20);
    u16* tb_b = tb + ((size_t)batch << 20);
    int tid = threadIdx.x, wid = tid >> 6, lane = tid & 63, lg = lane >> 4, lr = lane & 15;

    f32x4 zero = {0.f, 0.f, 0.f, 0.f};
    f32x4 acc[4][2];
#pragma unroll
    for (int ci = 0; ci < 4; ++ci)
#pragma unroll
        for (int nj = 0; nj < 2; ++nj) acc[ci][nj] = zero;

#pragma unroll
    for (int kc = 0; kc < 8; ++kc) {
        short8 bfr[2], afr[4];
#pragma unroll
        for (int nj = 0; nj < 2; ++nj)
            bfr[nj] = *(const short8*)(xf_b + (size_t)(n0 + (nj << 4) + lr) * 256 + (kc << 5) + (lg << 3));
#pragma unroll
        for (int ci = 0; ci < 4; ++ci)
            afr[ci] = *(const short8*)(Wbf + (size_t)((wid << 6) + (ci << 4) + lr) * 256 + (kc << 5) + (lg << 3));
#pragma unroll
        for (int ci = 0; ci < 4; ++ci) {
            acc[ci][0] = MFMA16(afr[ci], bfr[0], acc[ci][0]);
            acc[ci][1] = MFMA16(afr[ci], bfr[1], acc[ci][1]);
        }
    }
#pragma unroll
    for (int ci = 0; ci < 4; ++ci) {
        int cb = (wid << 6) + (ci << 4) + (lg << 2);
#pragma unroll
        for (int r = 0; r < 4; ++r) {
            float bv = bias[cb + r];
#pragma unroll
            for (int nj = 0; nj < 2; ++nj)
                tb_b[(size_t)(cb + r) * 4096 + n0 + (nj << 4) + lr] = f2bf(acc[ci][nj][r] + bv);
        }
    }
}

// ---------------- K3: fused  O[:,ntile] = T * P^T  --------------------------
// 256 blocks (1/CU), 512 threads (8 waves). BN=BM=64.
// Stage A waves: 2 row-halves x 4 col-tiles. afrag (block n-rows) persistent.
// Stage B waves: 4 c-groups x 2 n-groups; tb streamed from L2 (read-once/blk).
__global__ __launch_bounds__(512) void k_fused(const u16* __restrict__ xfT,
                                               const u16* __restrict__ tb,
                                               const float* __restrict__ nv2,
                                               float* __restrict__ out) {
    __shared__ __align__(16) u16 lds_x[64][264];   // m-tile of xfT, +8 pad
    __shared__ __align__(16) u16 lds_p[64][72];    // P[n][m], +8 pad

    int bid = blockIdx.x;
    // XCD swizzle: batch b's 64 blocks land on XCDs {2b, 2b+1} -> L2-resident panels
    int xcd = bid & 7, grp = bid >> 3;
    int batch = xcd >> 1;
    int nt = grp + 32 * (xcd & 1);
    int n0 = nt << 6;

    const u16* xf_b = xfT + ((size_t)batch << 20);
    const u16* tb_b = tb + ((size_t)batch << 20);
    const float* nv_b = nv2 + (batch << 12);
    float* out_b = out + ((size_t)batch << 20);

    int tid = threadIdx.x;
    int wid = tid >> 6, lane = tid & 63, lg = lane >> 4, lr = lane & 15;
    // stage A roles
    int rt2 = wid >> 2;   // row half (0..1)
    int tc = wid & 3;     // col tile (0..3)
    // stage B roles
    int cg = wid >> 1;    // c group (0..3): c-tiles [4cg,4cg+4)
    int ng = wid & 1;     // n group (0..1): n-tiles [2ng,2ng+2)

    // persistent A fragments: this block's 64 n-rows, full K=256
    short8 afrag[2][8];
#pragma unroll
    for (int ri = 0; ri < 2; ++ri) {
        const u16* p = xf_b + (size_t)(n0 + (rt2 << 5) + (ri << 4) + lr) * 256 + (lg << 3);
#pragma unroll
        for (int kc = 0; kc < 8; ++kc) afrag[ri][kc] = *(const short8*)(p + (kc << 5));
    }
    // per-row scales for this wave's S rows
    float nvn[2][4];
#pragma unroll
    for (int ri = 0; ri < 2; ++ri)
#pragma unroll
        for (int r = 0; r < 4; ++r)
            nvn[ri][r] = nv_b[n0 + (rt2 << 5) + (ri << 4) + (lg << 2) + r];

    f32x4 zero = {0.f, 0.f, 0.f, 0.f};
    f32x4 oacc[4][2];
#pragma unroll
    for (int ci = 0; ci < 4; ++ci)
#pragma unroll
        for (int nj = 0; nj < 2; ++nj) oacc[ci][nj] = zero;

    for (int mt = 0; mt < 64; ++mt) {
        int m0 = mt << 6;
        // ---- stage m-tile of xfT into LDS (reg-staged; prev readers done pre-B2) ----
        short8 stg[4];
#pragma unroll
        for (int s = 0; s < 4; ++s) {
            int idx = (s << 9) + tid;        // 0..2047, 16B each
            int row = idx >> 5, colg = idx & 31;
            stg[s] = *(const short8*)(xf_b + (size_t)(m0 + row) * 256 + (colg << 3));
        }
        float nvm = nv_b[m0 + (tc << 4) + lr];
#pragma unroll
        for (int s = 0; s < 4; ++s) {
            int idx = (s << 9) + tid;
            int row = idx >> 5, colg = idx & 31;
            *(short8*)(&lds_x[row][colg << 3]) = stg[s];
        }
        __syncthreads();   // B1: lds_x ready; prev-iter P readers done

        // ---- stage A: S = Xn^T * Xm  (2 row-tiles x 1 col-tile per wave) ----
        f32x4 sacc0 = zero, sacc1 = zero;
#pragma unroll
        for (int kc = 0; kc < 8; ++kc) {
            short8 bfr = *(const short8*)(&lds_x[(tc << 4) + lr][(kc << 5) + (lg << 3)]);
            sacc0 = MFMA16(afrag[0][kc], bfr, sacc0);
            sacc1 = MFMA16(afrag[1][kc], bfr, sacc1);
        }
        // P = relu(S)^2 * nv2[n] * nv2[m] -> bf16 -> lds_p[n][m]
#pragma unroll
        for (int r = 0; r < 4; ++r) {
            float s0 = fmaxf(sacc0[r], 0.f);
            s0 = s0 * s0 * nvn[0][r] * nvm;
            lds_p[(rt2 << 5) + (lg << 2) + r][(tc << 4) + lr] = f2bf(s0);
            float s1 = fmaxf(sacc1[r], 0.f);
            s1 = s1 * s1 * nvn[1][r] * nvm;
            lds_p[(rt2 << 5) + 16 + (lg << 2) + r][(tc << 4) + lr] = f2bf(s1);
        }
        __syncthreads();   // B2: P visible; stage-A lds_x reads done

        // ---- stage B: O += T[:,mtile] * P^T ----
        short8 pfr[2][2];
#pragma unroll
        for (int nj = 0; nj < 2; ++nj)
#pragma unroll
            for (int k2 = 0; k2 < 2; ++k2)
                pfr[nj][k2] = *(const short8*)(&lds_p[(((ng << 1) + nj) << 4) + lr][(k2 << 5) + (lg << 3)]);
#pragma unroll
        for (int ci = 0; ci < 4; ++ci) {
            const u16* tp = tb_b + (size_t)((((cg << 2) + ci) << 4) + lr) * 4096 + m0 + (lg << 3);
            short8 ta0 = *(const short8*)tp;
            short8 ta1 = *(const short8*)(tp + 32);
            oacc[ci][0] = MFMA16(ta0, pfr[0][0], oacc[ci][0]);
            oacc[ci][0] = MFMA16(ta1, pfr[0][1], oacc[ci][0]);
            oacc[ci][1] = MFMA16(ta0, pfr[1][0], oacc[ci][1]);
            oacc[ci][1] = MFMA16(ta1, pfr[1][1], oacc[ci][1]);
        }
    }

    // ---- epilogue: write O fp32 ----
#pragma unroll
    for (int ci = 0; ci < 4; ++ci) {
        int c = ((((cg << 2) + ci) << 4)) + (lg << 2);
#pragma unroll
        for (int nj = 0; nj < 2; ++nj) {
            int n = n0 + (((ng << 1) + nj) << 4) + lr;
            float* op = out_b + (size_t)c * 4096 + n;
#pragma unroll
            for (int r = 0; r < 4; ++r) op[(size_t)r * 4096] = oacc[ci][nj][r];
        }
    }
}

extern "C" void kernel_launch(void* const* d_in, const int* in_sizes, int n_in,
                              void* d_out, int out_size, void* d_ws, size_t ws_size,
                              hipStream_t stream) {
    const float* x = (const float*)d_in[0];     // (4,256,16,16,16) fp32
    const float* W = (const float*)d_in[1];     // (256,256) fp32
    const float* bias = (const float*)d_in[2];  // (256,) fp32
    float* out = (float*)d_out;

    char* ws = (char*)d_ws;
    u16* xfT = (u16*)ws;                                  // 8 MiB: [B][N][C] bf16
    u16* tb = (u16*)(ws + ((size_t)8 << 20));             // 8 MiB: [B][C][N] bf16
    u16* Wbf = (u16*)(ws + ((size_t)16 << 20));           // 128 KiB
    float* nv2 = (float*)(ws + ((size_t)16 << 20) + (128u << 10));  // 64 KiB

    hipLaunchKernelGGL(k_wconv, dim3(256), dim3(256), 0, stream, W, Wbf);
    hipLaunchKernelGGL(k_norm, dim3(64), dim3(256), 0, stream, x, nv2);
    hipLaunchKernelGGL(k_xpose, dim3(1024), dim3(256), 0, stream, x, xfT);
    hipLaunchKernelGGL(k_tgemm, dim3(512), dim3(256), 0, stream, Wbf, xfT, bias, tb);
    hipLaunchKernelGGL(k_fused, dim3(256), dim3(512), 0, stream, xfT, tb, nv2, out);
}

// Round 2
// 123.500 us; speedup vs baseline: 1.8660x; 1.8660x over previous
//
#include <hip/hip_runtime.h>
#include <hip/hip_bf16.h>

// Problem: B=4, C=256, N=4096 (16^3).
// out[b,c,n] = sum_m relu(cos(x_n,x_m))^2 * (W x + b)[c,m]
// Decomposition: xn = x/||x|| (bf16, precomputed) -> S = xn^T xn, P = relu(S)^2,
//                T[c,m] = nrm[m]*(W xn)[c,m] + b[c],   out = T * P^T.

typedef unsigned short u16;
typedef __attribute__((ext_vector_type(8))) short short8;   // 8 bf16 = 4 VGPRs
typedef __attribute__((ext_vector_type(4))) float f32x4;

#define MFMA16(a, b, c) __builtin_amdgcn_mfma_f32_16x16x32_bf16((a), (b), (c), 0, 0, 0)

__device__ __forceinline__ u16 f2bf(float f) {
    union { float f; unsigned u; } v; v.f = f;
    unsigned u = v.u;
    u += 0x7fffu + ((u >> 16) & 1u);   // RNE
    return (u16)(u >> 16);
}

// ---------------- K0: W (fp32 256x256) -> bf16 ----------------
__global__ void k_wconv(const float* __restrict__ W, u16* __restrict__ Wbf) {
    int i = blockIdx.x * 256 + threadIdx.x;
    Wbf[i] = f2bf(W[i]);
}

// ---------------- K1a: rs = 1/max(||x_n||,eps), nrm = ||x_n|| --------------
__global__ __launch_bounds__(256) void k_norm(const float* __restrict__ x,
                                              float* __restrict__ rs,
                                              float* __restrict__ nrm) {
    __shared__ float part[4][64];
    int bid = blockIdx.x;
    int b = bid >> 6, n0 = (bid & 63) << 6;
    int tid = threadIdx.x, q = tid >> 6, nl = tid & 63;
    const float* p = x + ((size_t)b << 20) + n0 + nl;
    float s = 0.f;
#pragma unroll 16
    for (int c = 0; c < 64; ++c) {
        float v = p[(size_t)((q << 6) + c) << 12];
        s += v * v;
    }
    part[q][nl] = s;
    __syncthreads();
    if (tid < 64) {
        float t = part[0][tid] + part[1][tid] + part[2][tid] + part[3][tid];
        float nr = sqrtf(t);
        int idx = (b << 12) + n0 + tid;
        nrm[idx] = nr;
        rs[idx] = 1.0f / fmaxf(nr, 1e-8f);
    }
}

// ---------------- K1b: xfn[b][n][c] = bf16(x[b][c][n] * rs[n]) --------------
__global__ __launch_bounds__(256) void k_xpose(const float* __restrict__ x,
                                               const float* __restrict__ rs,
                                               u16* __restrict__ xfn) {
    __shared__ u16 tl[64][68];
    __shared__ float rs_s[64];
    int bid = blockIdx.x;                    // 1024 = 4 * 4 * 64
    int b = bid >> 8, rem = bid & 255, ct = rem >> 6, nt = rem & 63;
    int c0 = ct << 6, n0 = nt << 6;
    int tid = threadIdx.x, rr = tid >> 6, cc = tid & 63;
    if (tid < 64) rs_s[tid] = rs[(b << 12) + n0 + tid];
    __syncthreads();
    const float* xp = x + ((size_t)b << 20) + (size_t)c0 * 4096 + n0;
    float rsv = rs_s[cc];
#pragma unroll
    for (int s = 0; s < 16; ++s) {
        int row = (s << 2) + rr;                       // c_loc
        tl[row][cc] = f2bf(xp[(size_t)row * 4096 + cc] * rsv);
    }
    __syncthreads();
    u16* op = xfn + ((size_t)b << 20) + (size_t)n0 * 256 + c0;
#pragma unroll
    for (int s = 0; s < 16; ++s) {
        int row = (s << 2) + rr;                       // n_loc
        op[(size_t)row * 256 + cc] = tl[cc][row];
    }
}

// ---------------- K2: tb[b][c][n] = nrm[n]*(W xn)[c,n] + bias[c] ------------
__global__ __launch_bounds__(256) void k_tgemm(const u16* __restrict__ Wbf,
                                               const u16* __restrict__ xfn,
                                               const float* __restrict__ bias,
                                               const float* __restrict__ nrm,
                                               u16* __restrict__ tb) {
    int bid = blockIdx.x;
    int batch = bid >> 7, nt = bid & 127;
    int n0 = nt << 5;
    const u16* xf_b = xfn + ((size_t)batch << 20);
    u16* tb_b = tb + ((size_t)batch << 20);
    int tid = threadIdx.x, wid = tid >> 6, lane = tid & 63, lg = lane >> 4, lr = lane & 15;

    f32x4 zero = {0.f, 0.f, 0.f, 0.f};
    f32x4 acc[4][2];
#pragma unroll
    for (int ci = 0; ci < 4; ++ci)
#pragma unroll
        for (int nj = 0; nj < 2; ++nj) acc[ci][nj] = zero;

#pragma unroll
    for (int kc = 0; kc < 8; ++kc) {
        short8 bfr[2], afr[4];
#pragma unroll
        for (int nj = 0; nj < 2; ++nj)
            bfr[nj] = *(const short8*)(xf_b + (size_t)(n0 + (nj << 4) + lr) * 256 + (kc << 5) + (lg << 3));
#pragma unroll
        for (int ci = 0; ci < 4; ++ci)
            afr[ci] = *(const short8*)(Wbf + (size_t)((wid << 6) + (ci << 4) + lr) * 256 + (kc << 5) + (lg << 3));
#pragma unroll
        for (int ci = 0; ci < 4; ++ci) {
            acc[ci][0] = MFMA16(afr[ci], bfr[0], acc[ci][0]);
            acc[ci][1] = MFMA16(afr[ci], bfr[1], acc[ci][1]);
        }
    }
    float nrmv[2];
#pragma unroll
    for (int nj = 0; nj < 2; ++nj)
        nrmv[nj] = nrm[(batch << 12) + n0 + (nj << 4) + lr];
#pragma unroll
    for (int ci = 0; ci < 4; ++ci) {
        int cb = (wid << 6) + (ci << 4) + (lg << 2);
#pragma unroll
        for (int r = 0; r < 4; ++r) {
            float bv = bias[cb + r];
#pragma unroll
            for (int nj = 0; nj < 2; ++nj)
                tb_b[(size_t)(cb + r) * 4096 + n0 + (nj << 4) + lr] = f2bf(acc[ci][nj][r] * nrmv[nj] + bv);
        }
    }
}

// ---------------- K3: fused  O[:,ntile] = T * P^T  --------------------------
// 256 blocks (1/CU), 512 threads (8 waves). BN=BM=64. Software-pipelined:
// lds_x double-buffered; tb fragments prefetched one iteration ahead; B2 is a
// raw lgkmcnt(0)+s_barrier so the tb prefetch survives the barrier (only LDS
// hazards cross B2: lds_x writes visible + lds_p reads complete — both lgkm).
__global__ __launch_bounds__(512, 2) void k_fused(const u16* __restrict__ xfn,
                                                  const u16* __restrict__ tb,
                                                  float* __restrict__ out) {
    __shared__ __align__(16) u16 lds_x[2][64][264];   // m-tile dbuf, +8 pad
    __shared__ __align__(16) u16 lds_p[64][72];       // P[n][m], +8 pad

    int bid = blockIdx.x;
    // XCD swizzle: batch b's 64 blocks -> XCDs {2b, 2b+1} (L2-resident panels)
    int xcd = bid & 7, grp = bid >> 3;
    int batch = xcd >> 1;
    int nt = grp + 32 * (xcd & 1);
    int n0 = nt << 6;

    const u16* xf_b = xfn + ((size_t)batch << 20);
    const u16* tb_b = tb + ((size_t)batch << 20);
    float* out_b = out + ((size_t)batch << 20);

    int tid = threadIdx.x;
    int wid = tid >> 6, lane = tid & 63, lg = lane >> 4, lr = lane & 15;
    int rt2 = wid >> 2, tc = wid & 3;   // stage A roles: row-half, col-tile
    // stage B role: wave wid owns c rows [32*wid, 32*wid+32)

    // persistent A fragments: block's 64 n-rows, full K=256 (64 VGPRs)
    short8 afrag[2][8];
#pragma unroll
    for (int ri = 0; ri < 2; ++ri) {
        const u16* p = xf_b + (size_t)(n0 + (rt2 << 5) + (ri << 4) + lr) * 256 + (lg << 3);
#pragma unroll
        for (int kc = 0; kc < 8; ++kc) afrag[ri][kc] = *(const short8*)(p + (kc << 5));
    }
    // prologue: stage m-tile 0 into lds_x[0]
#pragma unroll
    for (int s = 0; s < 4; ++s) {
        int idx = (s << 9) + tid, row = idx >> 5, colg = idx & 31;
        *(short8*)(&lds_x[0][row][colg << 3]) =
            *(const short8*)(xf_b + (size_t)row * 256 + (colg << 3));
    }
    // prologue: tb prefetch for mt=0
    short8 tbA[2][2], tbB[2][2];
#pragma unroll
    for (int ci = 0; ci < 2; ++ci)
#pragma unroll
        for (int k2 = 0; k2 < 2; ++k2)
            tbA[ci][k2] = *(const short8*)(tb_b + (size_t)((wid << 5) + (ci << 4) + lr) * 4096
                                           + (k2 << 5) + (lg << 3));
    f32x4 zero = {0.f, 0.f, 0.f, 0.f};
    f32x4 oacc[2][4];
#pragma unroll
    for (int ci = 0; ci < 2; ++ci)
#pragma unroll
        for (int nj = 0; nj < 4; ++nj) oacc[ci][nj] = zero;
    __syncthreads();

#define FBODY(MT, CUR, TBC, TBN)                                                           \
    {                                                                                      \
        short8 stg[4];                                                                     \
        if ((MT) + 1 < 64) {  /* issue next xf m-tile early */                             \
            _Pragma("unroll")                                                              \
            for (int s = 0; s < 4; ++s) {                                                  \
                int idx = (s << 9) + tid, row = idx >> 5, colg = idx & 31;                 \
                stg[s] = *(const short8*)(xf_b + (size_t)((((MT) + 1) << 6) + row) * 256   \
                                          + (colg << 3));                                  \
            }                                                                              \
        }                                                                                  \
        f32x4 sacc0 = zero, sacc1 = zero;                                                  \
        _Pragma("unroll")                                                                  \
        for (int kc = 0; kc < 8; ++kc) {                                                   \
            short8 bfr = *(const short8*)(&lds_x[CUR][(tc << 4) + lr][(kc << 5) + (lg << 3)]); \
            sacc0 = MFMA16(afrag[0][kc], bfr, sacc0);                                      \
            sacc1 = MFMA16(afrag[1][kc], bfr, sacc1);                                      \
        }                                                                                  \
        _Pragma("unroll")                                                                  \
        for (int r = 0; r < 4; ++r) {                                                      \
            float s0 = fmaxf(sacc0[r], 0.f);                                               \
            lds_p[(rt2 << 5) + (lg << 2) + r][(tc << 4) + lr] = f2bf(s0 * s0);             \
            float s1 = fmaxf(sacc1[r], 0.f);                                               \
            lds_p[(rt2 << 5) + 16 + (lg << 2) + r][(tc << 4) + lr] = f2bf(s1 * s1);        \
        }                                                                                  \
        __syncthreads(); /* B1: lds_p ready */                                             \
        short8 pfr[4][2];                                                                  \
        _Pragma("unroll")                                                                  \
        for (int nj = 0; nj < 4; ++nj) {                                                   \
            pfr[nj][0] = *(const short8*)(&lds_p[(nj << 4) + lr][(lg << 3)]);              \
            pfr[nj][1] = *(const short8*)(&lds_p[(nj << 4) + lr][32 + (lg << 3)]);         \
        }                                                                                  \
        _Pragma("unroll")                                                                  \
        for (int ci = 0; ci < 2; ++ci) {                                                   \
            _Pragma("unroll")                                                              \
            for (int nj = 0; nj < 4; ++nj) {                                               \
                oacc[ci][nj] = MFMA16(TBC[ci][0], pfr[nj][0], oacc[ci][nj]);               \
                oacc[ci][nj] = MFMA16(TBC[ci][1], pfr[nj][1], oacc[ci][nj]);               \
            }                                                                              \
        }                                                                                  \
        if ((MT) + 1 < 64) {                                                               \
            _Pragma("unroll")                                                              \
            for (int s = 0; s < 4; ++s) {  /* write prefetched tile to other buffer */     \
                int idx = (s << 9) + tid, row = idx >> 5, colg = idx & 31;                 \
                *(short8*)(&lds_x[(CUR) ^ 1][row][colg << 3]) = stg[s];                    \
            }                                                                              \
            _Pragma("unroll")                                                              \
            for (int ci = 0; ci < 2; ++ci) {  /* issue next tb fragments */                \
                _Pragma("unroll")                                                          \
                for (int k2 = 0; k2 < 2; ++k2)                                             \
                    TBN[ci][k2] = *(const short8*)(tb_b                                    \
                        + (size_t)((wid << 5) + (ci << 4) + lr) * 4096                     \
                        + (((MT) + 1) << 6) + (k2 << 5) + (lg << 3));                      \
            }                                                                              \
        }                                                                                  \
        asm volatile("s_waitcnt lgkmcnt(0)" ::: "memory"); /* B2: LDS-only drain */        \
        __builtin_amdgcn_sched_barrier(0);                                                 \
        __builtin_amdgcn_s_barrier();                                                      \
        __builtin_amdgcn_sched_barrier(0);                                                 \
    }

    for (int mt = 0; mt < 64; mt += 2) {
        FBODY(mt, 0, tbA, tbB);
        FBODY(mt + 1, 1, tbB, tbA);
    }
#undef FBODY

    // ---- epilogue: write O fp32 ----
#pragma unroll
    for (int ci = 0; ci < 2; ++ci) {
        int c = (wid << 5) + (ci << 4) + (lg << 2);
#pragma unroll
        for (int nj = 0; nj < 4; ++nj) {
            int n = n0 + (nj << 4) + lr;
            float* op = out_b + (size_t)c * 4096 + n;
#pragma unroll
            for (int r = 0; r < 4; ++r) op[(size_t)r * 4096] = oacc[ci][nj][r];
        }
    }
}

extern "C" void kernel_launch(void* const* d_in, const int* in_sizes, int n_in,
                              void* d_out, int out_size, void* d_ws, size_t ws_size,
                              hipStream_t stream) {
    const float* x = (const float*)d_in[0];     // (4,256,16,16,16) fp32
    const float* W = (const float*)d_in[1];     // (256,256) fp32
    const float* bias = (const float*)d_in[2];  // (256,) fp32
    float* out = (float*)d_out;

    char* ws = (char*)d_ws;
    u16* xfn = (u16*)ws;                                   // 8 MiB: [B][N][C] bf16, normalized
    u16* tb = (u16*)(ws + ((size_t)8 << 20));              // 8 MiB: [B][C][N] bf16
    u16* Wbf = (u16*)(ws + ((size_t)16 << 20));            // 128 KiB
    float* rs = (float*)(ws + ((size_t)16 << 20) + (128u << 10));   // 64 KiB
    float* nrm = (float*)(ws + ((size_t)16 << 20) + (192u << 10));  // 64 KiB

    hipLaunchKernelGGL(k_wconv, dim3(256), dim3(256), 0, stream, W, Wbf);
    hipLaunchKernelGGL(k_norm, dim3(256), dim3(256), 0, stream, x, rs, nrm);
    hipLaunchKernelGGL(k_xpose, dim3(1024), dim3(256), 0, stream, x, rs, xfn);
    hipLaunchKernelGGL(k_tgemm, dim3(512), dim3(256), 0, stream, Wbf, xfn, bias, nrm, tb);
    hipLaunchKernelGGL(k_fused, dim3(256), dim3(512), 0, stream, xfn, tb, out);
}